// Round 4
// baseline (805.600 us; speedup 1.0000x reference)
//
#include <hip/hip_runtime.h>

typedef __attribute__((ext_vector_type(4))) float f4;

#define NP 128      // nodes per graph
#define NE 2048     // edges per graph
#define NFEAT 128
#define NT 512

// Activation buffers: 32 words/row, chunk-XOR swizzle (chunk ^= row&7).
// A quad (4 lanes) reading a full row covers all 32 banks.
__device__ __forceinline__ float* rowc(float* buf, int row, int chunk) {
  return buf + row * 32 + (((chunk ^ row) & 7) << 2);
}
__device__ __forceinline__ float relem(const float* buf, int row, int d) {
  return buf[row * 32 + ((((d >> 2) ^ row) & 7) << 2) + (d & 3)];
}

// ---- aggregation: O[n] = dis[n]*(Z[n] + sum_in Z[src]) + bias. Quad per node
// (degree-sorted via order[]), lane q handles chunks 2q,2q+1. Padded-4 CSR,
// pad id 128 -> zero row of Z.
__device__ __forceinline__ void aggregate(float* Z, float* O,
    const float* __restrict__ bias, const unsigned char* inlist,
    const int* offs4, const int* indeg, const float* diss, const int* order, int t)
{
  const int n = order[t >> 2];
  const int q = t & 3;
  f4 s0 = *(const f4*)rowc(Z, n, 2 * q);
  f4 s1 = *(const f4*)rowc(Z, n, 2 * q + 1);
  const int ne = indeg[n];
  const unsigned* il = (const unsigned*)(inlist + offs4[n]);
  for (int p = 0; p < ne; p += 4) {
    const unsigned w = il[p >> 2];
#pragma unroll
    for (int b = 0; b < 4; ++b) {
      const int rr = (w >> (8 * b)) & 255;
      s0 += *(const f4*)rowc(Z, rr, 2 * q);
      s1 += *(const f4*)rowc(Z, rr, 2 * q + 1);
    }
  }
  const float d = diss[n];
  const f4 b0 = *(const f4*)(bias + q * 8);
  const f4 b1 = *(const f4*)(bias + q * 8 + 4);
  *(f4*)rowc(O, n, 2 * q) = s0 * d + b0;
  *(f4*)rowc(O, n, 2 * q + 1) = s1 * d + b1;
}

// ---- 32x32 matmul: Z[n][j] = (sum_k O[n][k]*W[k][j]) * dis[n]. Quad per node;
// row read redundantly (broadcast within quad); W from LDS (4-addr broadcast).
__device__ __forceinline__ void mm32(float* O, float* Z,
    const float* Wl, const float* diss, int t)
{
  const int n = t >> 2, q = t & 3;
  f4 av[8];
#pragma unroll
  for (int j = 0; j < 8; ++j) av[j] = *(const f4*)rowc(O, n, j);
  f4 a0 = {0.f, 0.f, 0.f, 0.f}, a1 = {0.f, 0.f, 0.f, 0.f};
#pragma unroll
  for (int k = 0; k < 32; ++k) {
    const float a = av[k >> 2][k & 3];
    const f4 w0 = *(const f4*)(Wl + k * 32 + q * 8);
    const f4 w1 = *(const f4*)(Wl + k * 32 + q * 8 + 4);
    a0 += a * w0;
    a1 += a * w1;
  }
  const float d = diss[n];
  *(f4*)rowc(Z, n, 2 * q) = a0 * d;
  *(f4*)rowc(Z, n, 2 * q + 1) = a1 * d;
}

__global__ __launch_bounds__(NT) void k1_gcn(
    const float* __restrict__ x, const float* __restrict__ eattr,
    const int* __restrict__ eidx,
    const float* __restrict__ W1, const float* __restrict__ b1,
    const float* __restrict__ W2, const float* __restrict__ b2,
    const float* __restrict__ W3, const float* __restrict__ b3,
    const float* __restrict__ W4, const float* __restrict__ b4,
    const float* __restrict__ c1w, const float* __restrict__ c1b,
    const float* __restrict__ c2w, const float* __restrict__ c2b,
    float* __restrict__ dense_out, int E_total)
{
  __shared__ float O1[4096];
  __shared__ float O2[4096];
  __shared__ float O3[4096];
  __shared__ float Z[4128];        // 129 rows; row 128 = zeros (CSR pad target)
  __shared__ float Wbuf[2048];     // W1-chunk (4KB) during L1; then W2|W3; then head bufs
  __shared__ float o4s[129];
  __shared__ float xedge[NP];
  __shared__ float diss[NP];
  __shared__ int indeg[NP];
  __shared__ int offs4[NP];
  __shared__ int curp[NP];
  __shared__ int order[NP];
  __shared__ unsigned char inlist[2432];  // sum ceil4(deg) <= 2048 + 3*128

  const int t = threadIdx.x;
  const int g = blockIdx.x;
  const int ebase = g * NE;
  const int nbase = g * NP;
  const int n = t >> 2, q = t & 3;  // quad-per-node mapping

  // early x prefetch (overlaps edge phase)
  const float* xrow = x + (size_t)(nbase + n) * NFEAT + q * 8;
  f4 pv0 = *(const f4*)(xrow);
  f4 pv1 = *(const f4*)(xrow + 4);

  if (t < NP) { xedge[t] = 0.f; indeg[t] = 0; curp[t] = 0; }
  if (t < 129) o4s[t] = 0.f;
  if (t < 32) Z[4096 + t] = 0.f;                           // zero pad row
  for (int w = t; w < 608; w += NT) ((int*)inlist)[w] = (int)0x80808080u;
  __syncthreads();

  // ---- edge pass 1: x_edge (over src), in-degree (over dst)
  int er[4], ec[4];
#pragma unroll
  for (int i = 0; i < 4; ++i) {
    const int e = t + i * NT;
    er[i] = eidx[ebase + e] - nbase;
    ec[i] = eidx[E_total + ebase + e] - nbase;
    atomicAdd(&xedge[er[i]], eattr[ebase + e]);
    atomicAdd(&indeg[ec[i]], 1);
  }
  __syncthreads();

  // ---- padded-4 CSR offsets; dis = rsqrt(1+deg); degree-rank order (desc)
  if (t < NP) {
    int s = 0;
    for (int m = 0; m < NP; ++m) s += (m < t) ? ((indeg[m] + 3) & ~3) : 0;
    offs4[t] = s;
    diss[t] = rsqrtf(1.0f + (float)indeg[t]);
    const int dn = indeg[t];
    int r = 0;
    for (int m = 0; m < NP; ++m) {
      const int dm = indeg[m];
      r += (dm > dn || (dm == dn && m < t)) ? 1 : 0;
    }
    order[r] = t;
  }
  __syncthreads();

  // ---- edge pass 2: fill dst-CSR src list (pad slots stay 128)
#pragma unroll
  for (int i = 0; i < 4; ++i) {
    const int p = atomicAdd(&curp[ec[i]], 1);
    inlist[offs4[ec[i]] + p] = (unsigned char)er[i];
  }

  // ---- layer 1: z1 = ([x | x_edge] @ W1) * dis -> Z. x chunks staged in Z
  // region; W1 chunk (32x32) staged in Wbuf. Register prefetch hides HBM.
  f4 a0 = {0.f, 0.f, 0.f, 0.f}, a1 = {0.f, 0.f, 0.f, 0.f};
  for (int fc = 0; fc < NFEAT; fc += 32) {
    __syncthreads();                                   // prev compute reads done
    *(f4*)rowc(Z, n, 2 * q) = pv0;
    *(f4*)rowc(Z, n, 2 * q + 1) = pv1;
    if (t < 256) {
      const int k = t >> 3, jq = t & 7;
      *(f4*)(Wbuf + k * 32 + jq * 4) = *(const f4*)(W1 + (size_t)(fc + k) * 32 + jq * 4);
    }
    if (fc < 96) {
      pv0 = *(const f4*)(xrow + fc + 32);
      pv1 = *(const f4*)(xrow + fc + 36);
    }
    __syncthreads();
    f4 av[8];
#pragma unroll
    for (int j = 0; j < 8; ++j) av[j] = *(const f4*)rowc(Z, n, j);
#pragma unroll
    for (int k = 0; k < 32; ++k) {
      const float a = av[k >> 2][k & 3];
      const f4 w0 = *(const f4*)(Wbuf + k * 32 + q * 8);
      const f4 w1 = *(const f4*)(Wbuf + k * 32 + q * 8 + 4);
      a0 += a * w0;
      a1 += a * w1;
    }
  }
  {
    const f4 wl0 = *(const f4*)(W1 + 128 * 32 + q * 8);
    const f4 wl1 = *(const f4*)(W1 + 128 * 32 + q * 8 + 4);
    const float xe = xedge[n], d = diss[n];
    a0 = (a0 + xe * wl0) * d;
    a1 = (a1 + xe * wl1) * d;
  }
  __syncthreads();                                     // all x-chunk reads done
  *(f4*)rowc(Z, n, 2 * q) = a0;
  *(f4*)rowc(Z, n, 2 * q + 1) = a1;
  if (t < 256) *(f4*)(Wbuf + t * 4) = *(const f4*)(W2 + t * 4);          // stage W2
  else *(f4*)(Wbuf + 1024 + (t - 256) * 4) = *(const f4*)(W3 + (t - 256) * 4); // W3
  __syncthreads();

  aggregate(Z, O1, b1, inlist, offs4, indeg, diss, order, t);  __syncthreads();
  mm32(O1, Z, Wbuf, diss, t);                                  __syncthreads();
  aggregate(Z, O2, b2, inlist, offs4, indeg, diss, order, t);  __syncthreads();
  mm32(O2, Z, Wbuf + 1024, diss, t);                           __syncthreads();
  aggregate(Z, O3, b3, inlist, offs4, indeg, diss, order, t);  __syncthreads();

  // ---- layer 4 (width 1): quad dot + shfl reduce
  {
    const f4 v0 = *(const f4*)rowc(O3, n, 2 * q);
    const f4 v1 = *(const f4*)rowc(O3, n, 2 * q + 1);
    const f4 w0 = *(const f4*)(W4 + q * 8);
    const f4 w1 = *(const f4*)(W4 + q * 8 + 4);
    float s = v0[0]*w0[0] + v0[1]*w0[1] + v0[2]*w0[2] + v0[3]*w0[3]
            + v1[0]*w1[0] + v1[1]*w1[1] + v1[2]*w1[2] + v1[3]*w1[3];
    s += __shfl_xor(s, 1);
    s += __shfl_xor(s, 2);
    if (q == 0) o4s[n] = s * diss[n];
  }
  __syncthreads();
  float s4 = 0.f;
  if (t < NP) {
    s4 = o4s[t];
    const int ne = indeg[t];
    const unsigned* il = (const unsigned*)(inlist + offs4[t]);
    for (int p = 0; p < ne; p += 4) {
      const unsigned w = il[p >> 2];
#pragma unroll
      for (int b = 0; b < 4; ++b) s4 += o4s[(w >> (8 * b)) & 255];
    }
  }
  __syncthreads();
  if (t < NP) o4s[t] = diss[t] * s4 + b4[0];
  __syncthreads();

  // ---- top-k (k=20) rank counting: matches lax.top_k (desc, stable ties)
  int* selidx  = (int*)Wbuf;       // Wbuf dead from here
  float* c1buf = Wbuf + 32;        // [16][20]
  float* mpbuf = Wbuf + 352;       // [16][10]
  if (t < NP) {
    const float sn = o4s[t];
    int cnt = 0;
    for (int m = 0; m < NP; ++m) {
      const float sm = o4s[m];
      cnt += (sm > sn || (sm == sn && m < t)) ? 1 : 0;
    }
    if (cnt < 20) selidx[cnt] = t;
  }
  __syncthreads();

  // ---- c1: [16 ch][20 k], relu
  if (t < 320) {
    const int k = t % 20, ch = t / 20;
    const int nd = selidx[k];
    const float* wr = c1w + ch * 97;
    float s = c1b[ch];
#pragma unroll 8
    for (int d = 0; d < 32; ++d) s += relem(O1, nd, d) * wr[d];
#pragma unroll 8
    for (int d = 0; d < 32; ++d) s += relem(O2, nd, d) * wr[32 + d];
#pragma unroll 8
    for (int d = 0; d < 32; ++d) s += relem(O3, nd, d) * wr[64 + d];
    s += o4s[nd] * wr[96];
    c1buf[ch * 20 + k] = fmaxf(s, 0.f);
  }
  __syncthreads();
  if (t < 160) {  // maxpool(2,2) -> [16][10]
    const int ch = t / 10, p = t % 10;
    mpbuf[ch * 10 + p] = fmaxf(c1buf[ch * 20 + 2 * p], c1buf[ch * 20 + 2 * p + 1]);
  }
  __syncthreads();
  if (t < 192) {  // conv1d 16->32, k=5 -> [32][6], relu
    const int oc = t / 6, tt = t % 6;
    float s = c2b[oc];
#pragma unroll
    for (int ic = 0; ic < 16; ++ic) {
      const float* wr = c2w + (oc * 16 + ic) * 5;
#pragma unroll
      for (int u = 0; u < 5; ++u) s += mpbuf[ic * 10 + tt + u] * wr[u];
    }
    dense_out[(size_t)g * 192 + t] = fmaxf(s, 0.f);
  }
}

// ---- K2: d1 = relu(dense[1024,192] @ out_w[192,1024] + out_b), 64x64 tiles
__global__ __launch_bounds__(256) void k2_d1(const float* __restrict__ dense,
    const float* __restrict__ out_w, const float* __restrict__ out_b,
    float* __restrict__ d1)
{
  __shared__ float As[32 * 68];  // [k][m] transposed
  __shared__ float Bs[32 * 68];  // [k][n]
  const int t = threadIdx.x;
  const int n0 = blockIdx.x * 64, m0 = blockIdx.y * 64;
  const int r = t & 15, c = t >> 4;
  float acc[4][4];
#pragma unroll
  for (int i = 0; i < 4; ++i)
#pragma unroll
    for (int u = 0; u < 4; ++u) acc[i][u] = 0.f;

  for (int kk = 0; kk < 192; kk += 32) {
    __syncthreads();
    {
      const int m = t >> 2;
      const int kq = (t & 3) * 2;
#pragma unroll
      for (int qq = 0; qq < 2; ++qq) {
        f4 v = *(const f4*)(dense + (size_t)(m0 + m) * 192 + kk + (kq + qq) * 4);
        const int k0 = (kq + qq) * 4;
        As[(k0+0)*68 + m] = v[0]; As[(k0+1)*68 + m] = v[1];
        As[(k0+2)*68 + m] = v[2]; As[(k0+3)*68 + m] = v[3];
      }
    }
    {
      const int k = t >> 3;
      const int nq = (t & 7) * 2;
#pragma unroll
      for (int qq = 0; qq < 2; ++qq) {
        f4 v = *(const f4*)(out_w + (size_t)(kk + k) * 1024 + n0 + (nq + qq) * 4);
        *(f4*)&Bs[k*68 + (nq + qq) * 4] = v;
      }
    }
    __syncthreads();
#pragma unroll
    for (int k = 0; k < 32; ++k) {
      f4 a = *(const f4*)&As[k*68 + r*4];
      f4 b = *(const f4*)&Bs[k*68 + c*4];
#pragma unroll
      for (int i = 0; i < 4; ++i)
#pragma unroll
        for (int u = 0; u < 4; ++u) acc[i][u] += a[i] * b[u];
    }
  }
  f4 bb = *(const f4*)(out_b + n0 + c*4);
#pragma unroll
  for (int i = 0; i < 4; ++i) {
    f4 o;
#pragma unroll
    for (int u = 0; u < 4; ++u) o[u] = fmaxf(acc[i][u] + bb[u], 0.f);
    *(f4*)(d1 + (size_t)(m0 + r*4 + i) * 1024 + n0 + c*4) = o;
  }
}

// ---- K3: d2 = d1[1024,1024] @ h1_w[1024,128] + h1_b, split-K with atomics
__global__ __launch_bounds__(256) void k3_init(const float* __restrict__ h1_b,
    float* __restrict__ d2)
{
  const int i = blockIdx.x * 256 + threadIdx.x;
  d2[i] = h1_b[i & 127];
}

__global__ __launch_bounds__(256) void k3_d2(const float* __restrict__ d1,
    const float* __restrict__ h1_w, float* __restrict__ d2)
{
  __shared__ float As[32 * 36];
  __shared__ float Bs[32 * 36];
  const int t = threadIdx.x;
  const int m0 = blockIdx.x * 32, n0 = blockIdx.y * 32, ks = blockIdx.z * 128;
  const int r = t & 15, c = t >> 4;
  float a00 = 0.f, a01 = 0.f, a10 = 0.f, a11 = 0.f;

  for (int kk = ks; kk < ks + 128; kk += 32) {
    __syncthreads();
    {
      const int m = t >> 3, kq = t & 7;
      f4 v = *(const f4*)(d1 + (size_t)(m0 + m) * 1024 + kk + kq * 4);
      const int k0 = kq * 4;
      As[(k0+0)*36 + m] = v[0]; As[(k0+1)*36 + m] = v[1];
      As[(k0+2)*36 + m] = v[2]; As[(k0+3)*36 + m] = v[3];
    }
    {
      const int k = t >> 3, nq = t & 7;
      f4 v = *(const f4*)(h1_w + (size_t)(kk + k) * 128 + n0 + nq * 4);
      *(f4*)&Bs[k*36 + nq*4] = v;
    }
    __syncthreads();
#pragma unroll
    for (int k = 0; k < 32; ++k) {
      const float a0 = As[k*36 + r*2], a1 = As[k*36 + r*2 + 1];
      const float b0 = Bs[k*36 + c*2], b1 = Bs[k*36 + c*2 + 1];
      a00 += a0*b0; a01 += a0*b1;
      a10 += a1*b0; a11 += a1*b1;
    }
  }
  atomicAdd(d2 + (size_t)(m0 + r*2 + 0) * 128 + n0 + c*2 + 0, a00);
  atomicAdd(d2 + (size_t)(m0 + r*2 + 0) * 128 + n0 + c*2 + 1, a01);
  atomicAdd(d2 + (size_t)(m0 + r*2 + 1) * 128 + n0 + c*2 + 0, a10);
  atomicAdd(d2 + (size_t)(m0 + r*2 + 1) * 128 + n0 + c*2 + 1, a11);
}

// ---- K4: logits = relu(d2) @ h2_w + h2_b, then log_softmax
__global__ __launch_bounds__(256) void k4_out(const float* __restrict__ d2,
    const float* __restrict__ h2_w, const float* __restrict__ h2_b,
    float* __restrict__ outp)
{
  __shared__ float lbuf[16][17];
  const int t = threadIdx.x;
  const int gl = t >> 4, cc = t & 15;
  const int g = blockIdx.x * 16 + gl;
  float s = h2_b[cc];
  for (int k4 = 0; k4 < 32; ++k4) {
    f4 v = *(const f4*)(d2 + (size_t)g * 128 + k4 * 4);
#pragma unroll
    for (int i = 0; i < 4; ++i) {
      const float rv = fmaxf(v[i], 0.f);
      s += rv * h2_w[(k4*4 + i) * 16 + cc];
    }
  }
  lbuf[gl][cc] = s;
  __syncthreads();
  float mx = -1e30f;
#pragma unroll
  for (int j = 0; j < 16; ++j) mx = fmaxf(mx, lbuf[gl][j]);
  float se = 0.f;
#pragma unroll
  for (int j = 0; j < 16; ++j) se += expf(lbuf[gl][j] - mx);
  outp[(size_t)g * 16 + cc] = s - mx - logf(se);
}

extern "C" void kernel_launch(void* const* d_in, const int* in_sizes, int n_in,
                              void* d_out, int out_size, void* d_ws, size_t ws_size,
                              hipStream_t stream) {
  const float* x     = (const float*)d_in[0];
  const float* eattr = (const float*)d_in[1];
  const int*   eidx  = (const int*)d_in[2];
  const float* W1 = (const float*)d_in[3];  const float* b1 = (const float*)d_in[4];
  const float* W2 = (const float*)d_in[5];  const float* b2 = (const float*)d_in[6];
  const float* W3 = (const float*)d_in[7];  const float* b3 = (const float*)d_in[8];
  const float* W4 = (const float*)d_in[9];  const float* b4 = (const float*)d_in[10];
  const float* c1w = (const float*)d_in[11]; const float* c1b = (const float*)d_in[12];
  const float* c2w = (const float*)d_in[13]; const float* c2b = (const float*)d_in[14];
  const float* out_w = (const float*)d_in[15]; const float* out_b = (const float*)d_in[16];
  const float* h1_w  = (const float*)d_in[17]; const float* h1_b  = (const float*)d_in[18];
  const float* h2_w  = (const float*)d_in[19]; const float* h2_b  = (const float*)d_in[20];

  const int E_total = in_sizes[1];            // 2,097,152 edges
  const int N_nodes = in_sizes[0] / NFEAT;    // 131,072
  const int G = N_nodes / NP;                 // 1024 graphs

  float* ws    = (float*)d_ws;
  float* dense = ws;                          // [G,192]
  float* d1    = ws + (size_t)G * 192;        // [G,1024]
  float* d2    = d1 + (size_t)G * 1024;       // [G,128]

  k1_gcn<<<G, NT, 0, stream>>>(x, eattr, eidx, W1, b1, W2, b2, W3, b3, W4, b4,
                               c1w, c1b, c2w, c2b, dense, E_total);
  k2_d1<<<dim3(16, G / 64), 256, 0, stream>>>(dense, out_w, out_b, d1);
  k3_init<<<(G * 128) / 256, 256, 0, stream>>>(h1_b, d2);
  k3_d2<<<dim3(G / 32, 4, 8), 256, 0, stream>>>(d1, h1_w, d2);
  k4_out<<<G / 16, 256, 0, stream>>>(d2, h2_w, h2_b, (float*)d_out);
}

// Round 5
// 286.878 us; speedup vs baseline: 2.8082x; 2.8082x over previous
//
#include <hip/hip_runtime.h>

typedef __attribute__((ext_vector_type(4))) float f4;
typedef __attribute__((ext_vector_type(2))) float f2;

#define NP 128      // nodes per graph
#define NE 2048     // edges per graph
#define NFEAT 128
#define LW 33       // row stride (words) for activation buffers
#define NT 512

// ---- in-place aggregation: zo[n] <- dis[n]*(zs[n] + sum_in zs[src]) + bias,
// 4 lanes/node (degree-rank ordered), 8-col slice each, f2 reads, padded-4 CSR
// (pad id 128 -> zero row). Optionally offloads result row to global gout.
__device__ __forceinline__ void aggregate(float* zo, const float* __restrict__ bias,
    const unsigned char* inlist, const int* offs4, const int* indeg,
    const float* diss, const int* order, int t, float* __restrict__ gout)
{
  const int n = order[t >> 2];
  const int j0 = (t & 3) * 8;
  float s[8];
#pragma unroll
  for (int u = 0; u < 4; ++u) {
    f2 v = *(const f2*)&zo[n*LW + j0 + 2*u];
    s[2*u] = v[0]; s[2*u+1] = v[1];
  }
  const int ps = offs4[n];
  const int pe = ps + ((indeg[n] + 3) & ~3);
  for (int p = ps; p < pe; p += 4) {
    const unsigned w = *(const unsigned*)(inlist + p);   // 4 neighbor ids
#pragma unroll
    for (int b = 0; b < 4; ++b) {
      const int rr = (w >> (8*b)) & 255;
#pragma unroll
      for (int u = 0; u < 4; ++u) {
        f2 v = *(const f2*)&zo[rr*LW + j0 + 2*u];
        s[2*u] += v[0]; s[2*u+1] += v[1];
      }
    }
  }
  __syncthreads();
  const float d = diss[n];
#pragma unroll
  for (int u = 0; u < 8; ++u) s[u] = d * s[u] + bias[j0 + u];
#pragma unroll
  for (int u = 0; u < 8; ++u) zo[n*LW + j0 + u] = s[u];
  if (gout) {
    f4 v0 = {s[0], s[1], s[2], s[3]};
    f4 v1 = {s[4], s[5], s[6], s[7]};
    *(f4*)(gout + n*32 + j0) = v0;
    *(f4*)(gout + n*32 + j0 + 4) = v1;
  }
  __syncthreads();
}

// ---- 32x32 matmul: dst[n][j] = (sum_k src[n][k]*W[k][j]) * dis[n]
// rows {n2, n2+64}, 4 cols/thread; W staged to Wl (stride 36), b32 src reads.
__device__ __forceinline__ void mm32(const float* src, float* dst,
    const float* __restrict__ Wg, float* Wl, const float* diss, int t)
{
  if (t < 256) {
    const int k = t >> 3, jq = t & 7;
    *(f4*)&Wl[k*36 + jq*4] = *(const f4*)(Wg + (size_t)k*32 + jq*4);
  }
  __syncthreads();
  const int n2 = t & 63, c4 = t >> 6;
  f4 a0 = {0.f,0.f,0.f,0.f}, a1 = {0.f,0.f,0.f,0.f};
#pragma unroll
  for (int k = 0; k < 32; ++k) {
    const f4 w = *(const f4*)&Wl[k*36 + c4*4];
    const float x0 = src[n2*LW + k];
    const float x1 = src[(n2+64)*LW + k];
    a0 += x0 * w;
    a1 += x1 * w;
  }
  const float d0 = diss[n2], d1 = diss[n2 + 64];
#pragma unroll
  for (int u = 0; u < 4; ++u) {
    dst[n2*LW + c4*4 + u] = a0[u] * d0;
    dst[(n2+64)*LW + c4*4 + u] = a1[u] * d1;
  }
  __syncthreads();
}

__global__ __launch_bounds__(NT, 4) void k1_gcn(
    const float* __restrict__ x, const float* __restrict__ eattr,
    const int* __restrict__ eidx,
    const float* __restrict__ W1, const float* __restrict__ b1,
    const float* __restrict__ W2, const float* __restrict__ b2,
    const float* __restrict__ W3, const float* __restrict__ b3,
    const float* __restrict__ W4, const float* __restrict__ b4,
    const float* __restrict__ c1w, const float* __restrict__ c1b,
    const float* __restrict__ c2w, const float* __restrict__ c2b,
    float* __restrict__ o1g_all, float* __restrict__ dense_out, int E_total)
{
  __shared__ float A[129*LW];      // ping: x-stage / zs1 / o1 / zs3 / o3
  __shared__ float B[129*LW];      // pong: x-stage / zs2 / o2 (held for head)
  __shared__ float Wl[32*36];      // W chunk; head overlays c1buf/mpbuf/s1stage
  __shared__ float o4s[129];
  __shared__ float xedge[NP];
  __shared__ float diss[NP];
  __shared__ int indeg[NP];
  __shared__ int offs4[NP];
  __shared__ int curp[NP];         // head overlays selidx
  __shared__ int order[NP];
  __shared__ unsigned char inlist[2432];  // sum ceil4(deg) <= 2048+3*128

  const int t = threadIdx.x;
  const int g = blockIdx.x;
  const int ebase = g * NE;
  const int nbase = g * NP;
  float* __restrict__ o1g = o1g_all + (size_t)g * (NP * 32);

  // early x prefetch (overlaps edge phase)
  const int sn = t >> 2, sq = t & 3;
  const float* xrow = x + (size_t)(nbase + sn) * NFEAT + sq * 8;
  f4 pv0 = *(const f4*)(xrow);
  f4 pv1 = *(const f4*)(xrow + 4);

  if (t < NP) { xedge[t] = 0.f; indeg[t] = 0; curp[t] = 0; }
  if (t < LW) { A[128*LW + t] = 0.f; B[128*LW + t] = 0.f; }
  if (t == 0) o4s[128] = 0.f;
  for (int w = t; w < 608; w += NT) ((int*)inlist)[w] = (int)0x80808080u;
  __syncthreads();

  // ---- edge pass 1: x_edge (over src), in-degree (over dst)
  int er[4], ec[4];
#pragma unroll
  for (int i = 0; i < 4; ++i) {
    const int e = t + i * NT;
    er[i] = eidx[ebase + e] - nbase;
    ec[i] = eidx[E_total + ebase + e] - nbase;
    atomicAdd(&xedge[er[i]], eattr[ebase + e]);
    atomicAdd(&indeg[ec[i]], 1);
  }
  __syncthreads();

  // ---- padded-4 CSR offsets; dis = rsqrt(1+deg); degree-rank order (desc)
  if (t < NP) {
    int s = 0;
    for (int m = 0; m < NP; ++m) s += (m < t) ? ((indeg[m] + 3) & ~3) : 0;
    offs4[t] = s;
    diss[t] = rsqrtf(1.0f + (float)indeg[t]);
    const int dn = indeg[t];
    int r = 0;
    for (int m = 0; m < NP; ++m) {
      const int dm = indeg[m];
      r += (dm > dn || (dm == dn && m < t)) ? 1 : 0;
    }
    order[r] = t;
  }
  __syncthreads();

  // ---- edge pass 2: fill dst-CSR src list (pad slots stay 128)
#pragma unroll
  for (int i = 0; i < 4; ++i) {
    const int p = atomicAdd(&curp[ec[i]], 1);
    inlist[offs4[ec[i]] + p] = (unsigned char)er[i];
  }

  // ---- layer 1: zs1 = ([x | x_edge] @ W1) * dis -> A; x chunks staged A/B alt.
  {
    const int n2 = t & 63, c4 = t >> 6;
    f4 a0 = {0.f,0.f,0.f,0.f}, a1 = {0.f,0.f,0.f,0.f};
    for (int fc = 0; fc < NFEAT; fc += 32) {
      float* xs = (fc & 32) ? B : A;
      __syncthreads();
      *(f4*)(xs + sn * LW + sq * 8) = pv0;
      *(f4*)(xs + sn * LW + sq * 8 + 4) = pv1;
      if (t < 256) {
        const int k = t >> 3, jq = t & 7;
        *(f4*)&Wl[k*36 + jq*4] = *(const f4*)(W1 + (size_t)(fc + k) * 32 + jq * 4);
      }
      if (fc < 96) {
        pv0 = *(const f4*)(xrow + fc + 32);
        pv1 = *(const f4*)(xrow + fc + 36);
      }
      __syncthreads();
#pragma unroll
      for (int k = 0; k < 32; ++k) {
        const f4 w = *(const f4*)&Wl[k*36 + c4*4];
        const float x0 = xs[n2*LW + k];
        const float x1 = xs[(n2+64)*LW + k];
        a0 += x0 * w;
        a1 += x1 * w;
      }
    }
    const f4 wl = *(const f4*)(W1 + 128*32 + c4*4);
    const float xe0 = xedge[n2], d0 = diss[n2];
    const float xe1 = xedge[n2+64], d1 = diss[n2+64];
    a0 = (a0 + xe0 * wl) * d0;
    a1 = (a1 + xe1 * wl) * d1;
    __syncthreads();                 // all chunk-3 (B) reads done
#pragma unroll
    for (int u = 0; u < 4; ++u) {    // zs1 -> A (scalar stores, safe alignment)
      A[n2*LW + c4*4 + u] = a0[u];
      A[(n2+64)*LW + c4*4 + u] = a1[u];
    }
  }
  __syncthreads();

  aggregate(A, b1, inlist, offs4, indeg, diss, order, t, o1g);      // A=o1 (+offload)
  mm32(A, B, W2, Wl, diss, t);                                      // B=zs2
  aggregate(B, b2, inlist, offs4, indeg, diss, order, t, nullptr);  // B=o2 (kept)
  mm32(B, A, W3, Wl, diss, t);                                      // A=zs3
  aggregate(A, b3, inlist, offs4, indeg, diss, order, t, nullptr);  // A=o3 (kept)

  // ---- layer 4 (width 1)
  if (t < NP) {
    float s = 0.f;
#pragma unroll
    for (int f = 0; f < 32; ++f) s += A[t*LW + f] * W4[f];
    o4s[t] = s * diss[t];
  }
  __syncthreads();
  float s4 = 0.f;
  if (t < NP) {
    s4 = o4s[t];
    const int ps = offs4[t], pe = ps + ((indeg[t] + 3) & ~3);
    for (int p = ps; p < pe; p += 4) {
      const unsigned w = *(const unsigned*)(inlist + p);
#pragma unroll
      for (int b = 0; b < 4; ++b) s4 += o4s[(w >> (8*b)) & 255];
    }
  }
  __syncthreads();
  if (t < NP) o4s[t] = diss[t] * s4 + b4[0];
  __syncthreads();

  // ---- top-k (k=20) rank counting: matches lax.top_k (desc, stable ties)
  int* selidx   = curp;            // curp dead
  float* c1buf  = Wl;              // [16][20]
  float* mpbuf  = Wl + 320;        // [16][10]
  float* s1stg  = Wl + 480;        // [20][33] staged o1 rows
  if (t < NP) {
    const float sn_ = o4s[t];
    int cnt = 0;
    for (int m = 0; m < NP; ++m) {
      const float sm = o4s[m];
      cnt += (sm > sn_ || (sm == sn_ && m < t)) ? 1 : 0;
    }
    if (cnt < 20) selidx[cnt] = t;
  }
  __syncthreads();

  // ---- stage selected o1 rows from global (L2-hot; same block wrote them)
  for (int w = t; w < 640; w += NT) {
    const int kk = w >> 5, col = w & 31;
    s1stg[kk * LW + col] = o1g[selidx[kk] * 32 + col];
  }
  __syncthreads();

  // ---- c1: [16 ch][20 k], relu   (o1 from stage, o2 from B, o3 from A)
  if (t < 320) {
    const int k = t % 20, ch = t / 20;
    const int nd = selidx[k];
    const float* wr = c1w + ch * 97;
    float s = c1b[ch];
#pragma unroll 8
    for (int d = 0; d < 32; ++d) s += s1stg[k*LW + d] * wr[d];
#pragma unroll 8
    for (int d = 0; d < 32; ++d) s += B[nd*LW + d] * wr[32 + d];
#pragma unroll 8
    for (int d = 0; d < 32; ++d) s += A[nd*LW + d] * wr[64 + d];
    s += o4s[nd] * wr[96];
    c1buf[ch * 20 + k] = fmaxf(s, 0.f);
  }
  __syncthreads();
  if (t < 160) {  // maxpool(2,2) -> [16][10]
    const int ch = t / 10, p = t % 10;
    mpbuf[ch * 10 + p] = fmaxf(c1buf[ch * 20 + 2*p], c1buf[ch * 20 + 2*p + 1]);
  }
  __syncthreads();
  if (t < 192) {  // conv1d 16->32, k=5 -> [32][6], relu
    const int oc = t / 6, tt = t % 6;
    float s = c2b[oc];
#pragma unroll
    for (int ic = 0; ic < 16; ++ic) {
      const float* wr = c2w + (oc * 16 + ic) * 5;
#pragma unroll
      for (int u = 0; u < 5; ++u) s += mpbuf[ic * 10 + tt + u] * wr[u];
    }
    dense_out[(size_t)g * 192 + t] = fmaxf(s, 0.f);
  }
}

// ---- K2: d1 = relu(dense[1024,192] @ out_w[192,1024] + out_b), 64x64 tiles
__global__ __launch_bounds__(256) void k2_d1(const float* __restrict__ dense,
    const float* __restrict__ out_w, const float* __restrict__ out_b,
    float* __restrict__ d1)
{
  __shared__ float As[32 * 68];  // [k][m] transposed
  __shared__ float Bs[32 * 68];  // [k][n]
  const int t = threadIdx.x;
  const int n0 = blockIdx.x * 64, m0 = blockIdx.y * 64;
  const int r = t & 15, c = t >> 4;
  float acc[4][4];
#pragma unroll
  for (int i = 0; i < 4; ++i)
#pragma unroll
    for (int u = 0; u < 4; ++u) acc[i][u] = 0.f;

  for (int kk = 0; kk < 192; kk += 32) {
    __syncthreads();
    {
      const int m = t >> 2;
      const int kq = (t & 3) * 2;
#pragma unroll
      for (int qq = 0; qq < 2; ++qq) {
        f4 v = *(const f4*)(dense + (size_t)(m0 + m) * 192 + kk + (kq + qq) * 4);
        const int k0 = (kq + qq) * 4;
        As[(k0+0)*68 + m] = v[0]; As[(k0+1)*68 + m] = v[1];
        As[(k0+2)*68 + m] = v[2]; As[(k0+3)*68 + m] = v[3];
      }
    }
    {
      const int k = t >> 3;
      const int nq = (t & 7) * 2;
#pragma unroll
      for (int qq = 0; qq < 2; ++qq) {
        f4 v = *(const f4*)(out_w + (size_t)(kk + k) * 1024 + n0 + (nq + qq) * 4);
        *(f4*)&Bs[k*68 + (nq + qq) * 4] = v;
      }
    }
    __syncthreads();
#pragma unroll
    for (int k = 0; k < 32; ++k) {
      f4 a = *(const f4*)&As[k*68 + r*4];
      f4 b = *(const f4*)&Bs[k*68 + c*4];
#pragma unroll
      for (int i = 0; i < 4; ++i)
#pragma unroll
        for (int u = 0; u < 4; ++u) acc[i][u] += a[i] * b[u];
    }
  }
  f4 bb = *(const f4*)(out_b + n0 + c*4);
#pragma unroll
  for (int i = 0; i < 4; ++i) {
    f4 o;
#pragma unroll
    for (int u = 0; u < 4; ++u) o[u] = fmaxf(acc[i][u] + bb[u], 0.f);
    *(f4*)(d1 + (size_t)(m0 + r*4 + i) * 1024 + n0 + c*4) = o;
  }
}

// ---- K3: d2 = d1[1024,1024] @ h1_w[1024,128] + h1_b, split-K with atomics
__global__ __launch_bounds__(256) void k3_init(const float* __restrict__ h1_b,
    float* __restrict__ d2)
{
  const int i = blockIdx.x * 256 + threadIdx.x;
  d2[i] = h1_b[i & 127];
}

__global__ __launch_bounds__(256) void k3_d2(const float* __restrict__ d1,
    const float* __restrict__ h1_w, float* __restrict__ d2)
{
  __shared__ float As[32 * 36];
  __shared__ float Bs[32 * 36];
  const int t = threadIdx.x;
  const int m0 = blockIdx.x * 32, n0 = blockIdx.y * 32, ks = blockIdx.z * 128;
  const int r = t & 15, c = t >> 4;
  float a00 = 0.f, a01 = 0.f, a10 = 0.f, a11 = 0.f;

  for (int kk = ks; kk < ks + 128; kk += 32) {
    __syncthreads();
    {
      const int m = t >> 3, kq = t & 7;
      f4 v = *(const f4*)(d1 + (size_t)(m0 + m) * 1024 + kk + kq * 4);
      const int k0 = kq * 4;
      As[(k0+0)*36 + m] = v[0]; As[(k0+1)*36 + m] = v[1];
      As[(k0+2)*36 + m] = v[2]; As[(k0+3)*36 + m] = v[3];
    }
    {
      const int k = t >> 3, nq = t & 7;
      f4 v = *(const f4*)(h1_w + (size_t)(kk + k) * 128 + n0 + nq * 4);
      *(f4*)&Bs[k*36 + nq*4] = v;
    }
    __syncthreads();
#pragma unroll
    for (int k = 0; k < 32; ++k) {
      const float a0 = As[k*36 + r*2], a1 = As[k*36 + r*2 + 1];
      const float b0 = Bs[k*36 + c*2], b1 = Bs[k*36 + c*2 + 1];
      a00 += a0*b0; a01 += a0*b1;
      a10 += a1*b0; a11 += a1*b1;
    }
  }
  atomicAdd(d2 + (size_t)(m0 + r*2 + 0) * 128 + n0 + c*2 + 0, a00);
  atomicAdd(d2 + (size_t)(m0 + r*2 + 0) * 128 + n0 + c*2 + 1, a01);
  atomicAdd(d2 + (size_t)(m0 + r*2 + 1) * 128 + n0 + c*2 + 0, a10);
  atomicAdd(d2 + (size_t)(m0 + r*2 + 1) * 128 + n0 + c*2 + 1, a11);
}

// ---- K4: logits = relu(d2) @ h2_w + h2_b, then log_softmax
__global__ __launch_bounds__(256) void k4_out(const float* __restrict__ d2,
    const float* __restrict__ h2_w, const float* __restrict__ h2_b,
    float* __restrict__ outp)
{
  __shared__ float lbuf[16][17];
  const int t = threadIdx.x;
  const int gl = t >> 4, cc = t & 15;
  const int g = blockIdx.x * 16 + gl;
  float s = h2_b[cc];
  for (int k4 = 0; k4 < 32; ++k4) {
    f4 v = *(const f4*)(d2 + (size_t)g * 128 + k4 * 4);
#pragma unroll
    for (int i = 0; i < 4; ++i) {
      const float rv = fmaxf(v[i], 0.f);
      s += rv * h2_w[(k4*4 + i) * 16 + cc];
    }
  }
  lbuf[gl][cc] = s;
  __syncthreads();
  float mx = -1e30f;
#pragma unroll
  for (int j = 0; j < 16; ++j) mx = fmaxf(mx, lbuf[gl][j]);
  float se = 0.f;
#pragma unroll
  for (int j = 0; j < 16; ++j) se += expf(lbuf[gl][j] - mx);
  outp[(size_t)g * 16 + cc] = s - mx - logf(se);
}

extern "C" void kernel_launch(void* const* d_in, const int* in_sizes, int n_in,
                              void* d_out, int out_size, void* d_ws, size_t ws_size,
                              hipStream_t stream) {
  const float* x     = (const float*)d_in[0];
  const float* eattr = (const float*)d_in[1];
  const int*   eidx  = (const int*)d_in[2];
  const float* W1 = (const float*)d_in[3];  const float* b1 = (const float*)d_in[4];
  const float* W2 = (const float*)d_in[5];  const float* b2 = (const float*)d_in[6];
  const float* W3 = (const float*)d_in[7];  const float* b3 = (const float*)d_in[8];
  const float* W4 = (const float*)d_in[9];  const float* b4 = (const float*)d_in[10];
  const float* c1w = (const float*)d_in[11]; const float* c1b = (const float*)d_in[12];
  const float* c2w = (const float*)d_in[13]; const float* c2b = (const float*)d_in[14];
  const float* out_w = (const float*)d_in[15]; const float* out_b = (const float*)d_in[16];
  const float* h1_w  = (const float*)d_in[17]; const float* h1_b  = (const float*)d_in[18];
  const float* h2_w  = (const float*)d_in[19]; const float* h2_b  = (const float*)d_in[20];

  const int E_total = in_sizes[1];            // 2,097,152 edges
  const int N_nodes = in_sizes[0] / NFEAT;    // 131,072
  const int G = N_nodes / NP;                 // 1024 graphs

  float* ws    = (float*)d_ws;
  float* dense = ws;                          // [G,192]
  float* d1    = ws + (size_t)G * 192;        // [G,1024]
  float* d2    = d1 + (size_t)G * 1024;       // [G,128]
  float* o1g   = d2 + (size_t)G * 128;        // [G,128,32] offloaded o1

  k1_gcn<<<G, NT, 0, stream>>>(x, eattr, eidx, W1, b1, W2, b2, W3, b3, W4, b4,
                               c1w, c1b, c2w, c2b, o1g, dense, E_total);
  k2_d1<<<dim3(16, G / 64), 256, 0, stream>>>(dense, out_w, out_b, d1);
  k3_init<<<(G * 128) / 256, 256, 0, stream>>>(h1_b, d2);
  k3_d2<<<dim3(G / 32, 4, 8), 256, 0, stream>>>(d1, h1_w, d2);
  k4_out<<<G / 16, 256, 0, stream>>>(d2, h2_w, h2_b, (float*)d_out);
}